// Round 3
// baseline (247.831 us; speedup 1.0000x reference)
//
#include <hip/hip_runtime.h>

typedef unsigned short u16;
typedef unsigned int u32;
typedef __attribute__((ext_vector_type(8))) short short8;
typedef __attribute__((ext_vector_type(4))) float f32x4;
typedef const __attribute__((address_space(1))) void gvoid;
typedef __attribute__((address_space(3))) void lvoid;

#define LRELU_SLOPE 0.2f
#define EPS 1e-8f

// ---------- helpers ----------
static __device__ inline u32 cvt_pk_bf16(float lo, float hi) {
    u32 r;
    asm volatile("v_cvt_pk_bf16_f32 %0, %1, %2" : "=v"(r) : "v"(lo), "v"(hi));
    return r;
}
static __device__ inline u16 f2bf(float x) {
    u32 u = __float_as_uint(x);
    u += 0x7FFF + ((u >> 16) & 1);
    return (u16)(u >> 16);
}

// ---------- conv_w (512x512 f32 [k][n]) -> wts bf16 [n][k], XOR-swizzle baked ----------
// within each 64-k block, original chunk c (8 elems) stored at slot (c ^ (n&7))
__global__ __launch_bounds__(256) void k_twt(const float* __restrict__ w, u16* __restrict__ wts) {
    int t = blockIdx.x * 256 + threadIdx.x;    // 262144
    int n = t >> 9, k = t & 511;
    int pos = (k & 448) + ((((k >> 3) ^ n) & 7) << 3) + (k & 7);
    wts[(size_t)n * 512 + pos] = f2bf(w[(size_t)k * 512 + n]);
}

// ---------- GEMM + noise/bias/lrelu + stats, 2-phase pipelined ----------
// tile 128x128, BK=64, 4 waves (2x2), 4x4 16x16x32 frags/wave
// A: reg-staged (f32->bf16 cvt in flight), double-buffered LDS, swizzled ds_write
// B: global_load_lds width-16 from pre-swizzled wts, double-buffered
__global__ __launch_bounds__(256, 2) void k_gemm(
    const float* __restrict__ x, const u16* __restrict__ wts,
    const float* __restrict__ noise, const float* __restrict__ nw,
    const float* __restrict__ bias, float* __restrict__ y,
    float* __restrict__ sum, float* __restrict__ sumsq)
{
    __shared__ __align__(16) u16 Al[2][128 * 64];
    __shared__ __align__(16) u16 Bl[2][128 * 64];
    const int tid  = threadIdx.x;
    const int lane = tid & 63;
    const int wid  = tid >> 6;
    const int wm   = wid >> 1, wn = wid & 1;
    const int wg   = blockIdx.x;
    const int swz  = (wg & 7) * 128 + (wg >> 3);   // XCD-contiguous (1024 % 8 == 0, bijective)
    const int m0   = (swz >> 2) * 128;
    const int n0   = (swz & 3) * 128;

    // A staging addresses: thread covers rows arow+j*32, LDS slot acp, global chunk ac
    const int arow = tid >> 3;                 // 0..31
    const int acp  = tid & 7;
    const int ac   = acp ^ (arow & 7);
    const float* asrc = x + (size_t)(m0 + arow) * 512 + ac * 8;
    // B staging: per-wave 32 rows, 4 gload_lds calls of 1KB
    const size_t brow0 = (size_t)(n0 + wid * 32 + (lane >> 3)) * 512 + (lane & 7) * 8;

    f32x4 acc[4][4] = {};
    float4 pa[8];

    // ---- prologue: stage tile 0 ----
    #pragma unroll
    for (int j = 0; j < 4; ++j) {
        pa[2 * j]     = *(const float4*)(asrc + (size_t)j * 32 * 512);
        pa[2 * j + 1] = *(const float4*)(asrc + (size_t)j * 32 * 512 + 4);
    }
    #pragma unroll
    for (int i = 0; i < 4; ++i)
        __builtin_amdgcn_global_load_lds((gvoid*)(wts + brow0 + (size_t)i * 8 * 512),
                                         (lvoid*)((char*)Bl[0] + wid * 4096 + i * 1024), 16, 0, 0);
    #pragma unroll
    for (int j = 0; j < 4; ++j) {
        uint4 o;
        o.x = cvt_pk_bf16(pa[2 * j].x, pa[2 * j].y);
        o.y = cvt_pk_bf16(pa[2 * j].z, pa[2 * j].w);
        o.z = cvt_pk_bf16(pa[2 * j + 1].x, pa[2 * j + 1].y);
        o.w = cvt_pk_bf16(pa[2 * j + 1].z, pa[2 * j + 1].w);
        *(uint4*)((char*)Al[0] + (arow + j * 32) * 128 + acp * 16) = o;
    }
    __syncthreads();

    for (int t = 0; t < 8; ++t) {
        const int cb = t & 1, nb = cb ^ 1;
        const int kb = (t + 1) * 64;
        if (t < 7) {
            // issue next-tile loads BEFORE compute (latency hides under MFMA)
            #pragma unroll
            for (int j = 0; j < 4; ++j) {
                pa[2 * j]     = *(const float4*)(asrc + (size_t)j * 32 * 512 + kb);
                pa[2 * j + 1] = *(const float4*)(asrc + (size_t)j * 32 * 512 + kb + 4);
            }
            #pragma unroll
            for (int i = 0; i < 4; ++i)
                __builtin_amdgcn_global_load_lds((gvoid*)(wts + brow0 + (size_t)i * 8 * 512 + kb),
                                                 (lvoid*)((char*)Bl[nb] + wid * 4096 + i * 1024), 16, 0, 0);
        }
        // ---- compute on buffer cb ----
        #pragma unroll
        for (int ks = 0; ks < 2; ++ks) {
            short8 af[4], bf[4];
            const int cidx = ks * 4 + (lane >> 4);
            #pragma unroll
            for (int mi = 0; mi < 4; ++mi) {
                int r = wm * 64 + mi * 16 + (lane & 15);
                af[mi] = *(const short8*)((char*)Al[cb] + r * 128 + ((cidx ^ (r & 7)) * 16));
            }
            #pragma unroll
            for (int ni = 0; ni < 4; ++ni) {
                int r = wn * 64 + ni * 16 + (lane & 15);
                bf[ni] = *(const short8*)((char*)Bl[cb] + r * 128 + ((cidx ^ (r & 7)) * 16));
            }
            #pragma unroll
            for (int mi = 0; mi < 4; ++mi)
                #pragma unroll
                for (int ni = 0; ni < 4; ++ni)
                    acc[mi][ni] = __builtin_amdgcn_mfma_f32_16x16x32_bf16(
                        af[mi], bf[ni], acc[mi][ni], 0, 0, 0);
        }
        if (t < 7) {
            // cvt + write next A tile (other buffer; safe while others still compute cb)
            #pragma unroll
            for (int j = 0; j < 4; ++j) {
                uint4 o;
                o.x = cvt_pk_bf16(pa[2 * j].x, pa[2 * j].y);
                o.y = cvt_pk_bf16(pa[2 * j].z, pa[2 * j].w);
                o.z = cvt_pk_bf16(pa[2 * j + 1].x, pa[2 * j + 1].y);
                o.w = cvt_pk_bf16(pa[2 * j + 1].z, pa[2 * j + 1].w);
                *(uint4*)((char*)Al[nb] + (arow + j * 32) * 128 + acp * 16) = o;
            }
            __syncthreads();   // one barrier per K-step; drains gload_lds + ds_writes
        }
    }

    // ---- epilogue: noise + bias + lrelu, write y, accumulate per-(b,f) stats ----
    const int b = m0 >> 12;
    float nwv[4], bv[4];
    int colb[4];
    #pragma unroll
    for (int ni = 0; ni < 4; ++ni) {
        int col = n0 + wn * 64 + ni * 16 + (lane & 15);
        colb[ni] = col;
        nwv[ni] = nw[col];
        bv[ni]  = bias[col];
    }
    float ls[4] = {0, 0, 0, 0}, lq[4] = {0, 0, 0, 0};
    #pragma unroll
    for (int mi = 0; mi < 4; ++mi) {
        int rbase = m0 + wm * 64 + mi * 16 + (lane >> 4) * 4;
        #pragma unroll
        for (int r = 0; r < 4; ++r) {
            int row = rbase + r;
            float nz = noise[row];
            #pragma unroll
            for (int ni = 0; ni < 4; ++ni) {
                float v = acc[mi][ni][r] + nwv[ni] * nz + bv[ni];
                v = v > 0.0f ? v : LRELU_SLOPE * v;
                y[(size_t)row * 512 + colb[ni]] = v;
                ls[ni] += v;
                lq[ni] += v * v;
            }
        }
    }
    #pragma unroll
    for (int ni = 0; ni < 4; ++ni) {
        float s = ls[ni], q = lq[ni];
        s += __shfl_xor(s, 16); s += __shfl_xor(s, 32);
        q += __shfl_xor(q, 16); q += __shfl_xor(q, 32);
        if ((lane >> 4) == 0) {
            atomicAdd(&sum[b * 512 + colb[ni]], s);
            atomicAdd(&sumsq[b * 512 + colb[ni]], q);
        }
    }
}

// ---------- gamma/beta dense GEMM + stats finalize: A=(1+g)*rsqrt(var+eps), C=be-mu*A ----------
__global__ __launch_bounds__(256) void k_gb(
    const float* __restrict__ dl, const float* __restrict__ dw,
    const float* __restrict__ db, const float* __restrict__ sum,
    const float* __restrict__ sumsq, float* __restrict__ As, float* __restrict__ Cs)
{
    int f = blockIdx.x * 256 + threadIdx.x;    // 0..511 (grid.x = 2)
    int b = blockIdx.y;                        // 0..7
    const float* dlb = dl + (size_t)b * 512;
    float g  = db[f];
    float be = db[512 + f];
    #pragma unroll 4
    for (int k = 0; k < 512; ++k) {
        float dv = dlb[k];
        g  = fmaf(dv, dw[(size_t)k * 1024 + f], g);
        be = fmaf(dv, dw[(size_t)k * 1024 + 512 + f], be);
    }
    int t = b * 512 + f;
    float mu  = sum[t]   * (1.0f / 4096.0f);
    float var = sumsq[t] * (1.0f / 4096.0f) - mu * mu;
    float A = rsqrtf(var + EPS) * (1.0f + g);
    As[t] = A;
    Cs[t] = be - mu * A;
}

// ---------- in-place normalize + scale/shift ----------
__global__ __launch_bounds__(256) void k_norm(
    float* __restrict__ y, const float* __restrict__ As, const float* __restrict__ Cs)
{
    size_t i8 = (size_t)(blockIdx.x * 256 + threadIdx.x) * 8;
    int row = (int)(i8 >> 9);
    int f0  = (int)(i8 & 511);
    int b   = row >> 12;
    const float4 a0 = *(const float4*)(As + b * 512 + f0);
    const float4 a1 = *(const float4*)(As + b * 512 + f0 + 4);
    const float4 c0 = *(const float4*)(Cs + b * 512 + f0);
    const float4 c1 = *(const float4*)(Cs + b * 512 + f0 + 4);
    float4 v0 = *(float4*)(y + i8);
    float4 v1 = *(float4*)(y + i8 + 4);
    v0.x = v0.x * a0.x + c0.x;  v0.y = v0.y * a0.y + c0.y;
    v0.z = v0.z * a0.z + c0.z;  v0.w = v0.w * a0.w + c0.w;
    v1.x = v1.x * a1.x + c1.x;  v1.y = v1.y * a1.y + c1.y;
    v1.z = v1.z * a1.z + c1.z;  v1.w = v1.w * a1.w + c1.w;
    *(float4*)(y + i8)     = v0;
    *(float4*)(y + i8 + 4) = v1;
}

extern "C" void kernel_launch(void* const* d_in, const int* in_sizes, int n_in,
                              void* d_out, int out_size, void* d_ws, size_t ws_size,
                              hipStream_t stream) {
    const float* x     = (const float*)d_in[0];
    const float* dl    = (const float*)d_in[1];
    const float* noise = (const float*)d_in[2];
    const float* w     = (const float*)d_in[3];
    const float* nw    = (const float*)d_in[4];
    const float* bias  = (const float*)d_in[5];
    const float* dw    = (const float*)d_in[6];
    const float* db    = (const float*)d_in[7];
    float* out = (float*)d_out;

    char* ws = (char*)d_ws;
    u16*   wts   = (u16*)ws;                       // 512 KB
    float* sum   = (float*)(ws + 524288);          // 16 KB
    float* sumsq = (float*)(ws + 540672);          // 16 KB (adjacent)
    float* As    = (float*)(ws + 557056);          // 16 KB
    float* Cs    = (float*)(ws + 573440);          // 16 KB

    hipMemsetAsync(sum, 0, 32768, stream);         // zero sum+sumsq
    k_twt <<<1024, 256, 0, stream>>>(w, wts);
    k_gemm<<<1024, 256, 0, stream>>>(x, wts, noise, nw, bias, out, sum, sumsq);
    k_gb  <<<dim3(2, 8), 256, 0, stream>>>(dl, dw, db, sum, sumsq, As, Cs);
    k_norm<<<8192, 256, 0, stream>>>(out, As, Cs);
}

// Round 4
// 179.218 us; speedup vs baseline: 1.3828x; 1.3828x over previous
//
#include <hip/hip_runtime.h>

typedef unsigned short u16;
typedef unsigned int u32;
typedef __attribute__((ext_vector_type(8))) short short8;
typedef __attribute__((ext_vector_type(4))) float f32x4;
typedef const __attribute__((address_space(1))) void gvoid;
typedef __attribute__((address_space(3))) void lvoid;

#define LRELU_SLOPE 0.2f
#define EPS 1e-8f

// ---------- helpers ----------
static __device__ inline u32 cvt_pk_bf16(float lo, float hi) {
    u32 r;
    asm volatile("v_cvt_pk_bf16_f32 %0, %1, %2" : "=v"(r) : "v"(lo), "v"(hi));
    return r;
}
static __device__ inline u16 f2bf(float x) {
    u32 u = __float_as_uint(x);
    u += 0x7FFF + ((u >> 16) & 1);
    return (u16)(u >> 16);
}

// ---------- k_prep: 3 roles by blockIdx ----------
// blocks 0..1023   : conv_w (512x512 f32 [k][n]) -> wts bf16 [n][k], XOR-swizzle baked
// blocks 1024..1151: dense gamma/beta GEMM, 8-way k-split + LDS reduce -> gbuf (g,be incl db)
// block  1152      : zero sum/sumsq (32 KB)
__global__ __launch_bounds__(256) void k_prep(
    const float* __restrict__ w, u16* __restrict__ wts,
    const float* __restrict__ dl, const float* __restrict__ dw,
    const float* __restrict__ db, float* __restrict__ gbuf,
    float* __restrict__ zbase)
{
    __shared__ float sg[256], sb[256];
    const int bx  = blockIdx.x;
    const int tid = threadIdx.x;
    if (bx < 1024) {
        int t = bx * 256 + tid;                 // 262144
        int n = t >> 9, k = t & 511;
        int pos = (k & 448) + ((((k >> 3) ^ n) & 7) << 3) + (k & 7);
        wts[(size_t)n * 512 + pos] = f2bf(w[(size_t)k * 512 + n]);
    } else if (bx < 1152) {
        int idx = bx - 1024;                    // 0..127
        int b   = idx >> 4;                     // 0..7
        int f   = (idx & 15) * 32 + (tid & 31); // 0..511
        int kc  = tid >> 5;                     // 0..7, 64 k each
        const float* dlb = dl + (size_t)b * 512;
        float g = 0.0f, be = 0.0f;
        #pragma unroll 16
        for (int i = 0; i < 64; ++i) {
            int k = kc * 64 + i;
            float dv = dlb[k];
            g  = fmaf(dv, dw[(size_t)k * 1024 + f], g);
            be = fmaf(dv, dw[(size_t)k * 1024 + 512 + f], be);
        }
        sg[tid] = g; sb[tid] = be;
        __syncthreads();
        if (tid < 32) {
            float gs = db[f], bs = db[512 + f];
            #pragma unroll
            for (int q = 0; q < 8; ++q) { gs += sg[tid + 32 * q]; bs += sb[tid + 32 * q]; }
            gbuf[(size_t)b * 1024 + f]       = gs;
            gbuf[(size_t)b * 1024 + 512 + f] = bs;
        }
    } else {
        float4 z = {0.0f, 0.0f, 0.0f, 0.0f};
        float4* p = (float4*)zbase;             // sum+sumsq contiguous, 2048 float4
        #pragma unroll
        for (int i = 0; i < 8; ++i)
            p[tid + i * 256] = z;
    }
}

// ---------- GEMM + noise/bias/lrelu + stats, 2-phase pipelined ----------
// tile 128x128, BK=64, 4 waves (2x2), 4x4 16x16x32 frags/wave
__global__ __launch_bounds__(256, 2) void k_gemm(
    const float* __restrict__ x, const u16* __restrict__ wts,
    const float* __restrict__ noise, const float* __restrict__ nw,
    const float* __restrict__ bias, float* __restrict__ y,
    float* __restrict__ sum, float* __restrict__ sumsq)
{
    __shared__ __align__(16) u16 Al[2][128 * 64];
    __shared__ __align__(16) u16 Bl[2][128 * 64];
    const int tid  = threadIdx.x;
    const int lane = tid & 63;
    const int wid  = tid >> 6;
    const int wm   = wid >> 1, wn = wid & 1;
    const int wg   = blockIdx.x;
    const int swz  = (wg & 7) * 128 + (wg >> 3);   // XCD-contiguous (1024 % 8 == 0, bijective)
    const int m0   = (swz >> 2) * 128;
    const int n0   = (swz & 3) * 128;

    const int arow = tid >> 3;                 // 0..31
    const int acp  = tid & 7;
    const int ac   = acp ^ (arow & 7);
    const float* asrc = x + (size_t)(m0 + arow) * 512 + ac * 8;
    const size_t brow0 = (size_t)(n0 + wid * 32 + (lane >> 3)) * 512 + (lane & 7) * 8;

    f32x4 acc[4][4] = {};
    float4 pa[8];

    #pragma unroll
    for (int j = 0; j < 4; ++j) {
        pa[2 * j]     = *(const float4*)(asrc + (size_t)j * 32 * 512);
        pa[2 * j + 1] = *(const float4*)(asrc + (size_t)j * 32 * 512 + 4);
    }
    #pragma unroll
    for (int i = 0; i < 4; ++i)
        __builtin_amdgcn_global_load_lds((gvoid*)(wts + brow0 + (size_t)i * 8 * 512),
                                         (lvoid*)((char*)Bl[0] + wid * 4096 + i * 1024), 16, 0, 0);
    #pragma unroll
    for (int j = 0; j < 4; ++j) {
        uint4 o;
        o.x = cvt_pk_bf16(pa[2 * j].x, pa[2 * j].y);
        o.y = cvt_pk_bf16(pa[2 * j].z, pa[2 * j].w);
        o.z = cvt_pk_bf16(pa[2 * j + 1].x, pa[2 * j + 1].y);
        o.w = cvt_pk_bf16(pa[2 * j + 1].z, pa[2 * j + 1].w);
        *(uint4*)((char*)Al[0] + (arow + j * 32) * 128 + acp * 16) = o;
    }
    __syncthreads();

    for (int t = 0; t < 8; ++t) {
        const int cb = t & 1, nb = cb ^ 1;
        const int kb = (t + 1) * 64;
        if (t < 7) {
            #pragma unroll
            for (int j = 0; j < 4; ++j) {
                pa[2 * j]     = *(const float4*)(asrc + (size_t)j * 32 * 512 + kb);
                pa[2 * j + 1] = *(const float4*)(asrc + (size_t)j * 32 * 512 + kb + 4);
            }
            #pragma unroll
            for (int i = 0; i < 4; ++i)
                __builtin_amdgcn_global_load_lds((gvoid*)(wts + brow0 + (size_t)i * 8 * 512 + kb),
                                                 (lvoid*)((char*)Bl[nb] + wid * 4096 + i * 1024), 16, 0, 0);
        }
        #pragma unroll
        for (int ks = 0; ks < 2; ++ks) {
            short8 af[4], bf[4];
            const int cidx = ks * 4 + (lane >> 4);
            #pragma unroll
            for (int mi = 0; mi < 4; ++mi) {
                int r = wm * 64 + mi * 16 + (lane & 15);
                af[mi] = *(const short8*)((char*)Al[cb] + r * 128 + ((cidx ^ (r & 7)) * 16));
            }
            #pragma unroll
            for (int ni = 0; ni < 4; ++ni) {
                int r = wn * 64 + ni * 16 + (lane & 15);
                bf[ni] = *(const short8*)((char*)Bl[cb] + r * 128 + ((cidx ^ (r & 7)) * 16));
            }
            #pragma unroll
            for (int mi = 0; mi < 4; ++mi)
                #pragma unroll
                for (int ni = 0; ni < 4; ++ni)
                    acc[mi][ni] = __builtin_amdgcn_mfma_f32_16x16x32_bf16(
                        af[mi], bf[ni], acc[mi][ni], 0, 0, 0);
        }
        if (t < 7) {
            #pragma unroll
            for (int j = 0; j < 4; ++j) {
                uint4 o;
                o.x = cvt_pk_bf16(pa[2 * j].x, pa[2 * j].y);
                o.y = cvt_pk_bf16(pa[2 * j].z, pa[2 * j].w);
                o.z = cvt_pk_bf16(pa[2 * j + 1].x, pa[2 * j + 1].y);
                o.w = cvt_pk_bf16(pa[2 * j + 1].z, pa[2 * j + 1].w);
                *(uint4*)((char*)Al[nb] + (arow + j * 32) * 128 + acp * 16) = o;
            }
            __syncthreads();
        }
    }

    // ---- epilogue: noise + bias + lrelu, write y, accumulate per-(b,f) stats ----
    const int b = m0 >> 12;
    float nwv[4], bv[4];
    int colb[4];
    #pragma unroll
    for (int ni = 0; ni < 4; ++ni) {
        int col = n0 + wn * 64 + ni * 16 + (lane & 15);
        colb[ni] = col;
        nwv[ni] = nw[col];
        bv[ni]  = bias[col];
    }
    float ls[4] = {0, 0, 0, 0}, lq[4] = {0, 0, 0, 0};
    #pragma unroll
    for (int mi = 0; mi < 4; ++mi) {
        int rbase = m0 + wm * 64 + mi * 16 + (lane >> 4) * 4;
        #pragma unroll
        for (int r = 0; r < 4; ++r) {
            int row = rbase + r;
            float nz = noise[row];
            #pragma unroll
            for (int ni = 0; ni < 4; ++ni) {
                float v = acc[mi][ni][r] + nwv[ni] * nz + bv[ni];
                v = v > 0.0f ? v : LRELU_SLOPE * v;
                y[(size_t)row * 512 + colb[ni]] = v;
                ls[ni] += v;
                lq[ni] += v * v;
            }
        }
    }
    #pragma unroll
    for (int ni = 0; ni < 4; ++ni) {
        float s = ls[ni], q = lq[ni];
        s += __shfl_xor(s, 16); s += __shfl_xor(s, 32);
        q += __shfl_xor(q, 16); q += __shfl_xor(q, 32);
        if ((lane >> 4) == 0) {
            atomicAdd(&sum[b * 512 + colb[ni]], s);
            atomicAdd(&sumsq[b * 512 + colb[ni]], q);
        }
    }
}

// ---------- in-place normalize: finalize A,C per thread from cached tables, apply ----------
__global__ __launch_bounds__(256) void k_norm(
    float* __restrict__ y, const float* __restrict__ sum, const float* __restrict__ sumsq,
    const float* __restrict__ gbuf)
{
    size_t i8 = (size_t)(blockIdx.x * 256 + threadIdx.x) * 8;
    int row = (int)(i8 >> 9);
    int f0  = (int)(i8 & 511);
    int b   = row >> 12;
    int t   = b * 512 + f0;
    float s[8], q[8], g[8], be[8];
    *(float4*)(s)      = *(const float4*)(sum + t);
    *(float4*)(s + 4)  = *(const float4*)(sum + t + 4);
    *(float4*)(q)      = *(const float4*)(sumsq + t);
    *(float4*)(q + 4)  = *(const float4*)(sumsq + t + 4);
    *(float4*)(g)      = *(const float4*)(gbuf + b * 1024 + f0);
    *(float4*)(g + 4)  = *(const float4*)(gbuf + b * 1024 + f0 + 4);
    *(float4*)(be)     = *(const float4*)(gbuf + b * 1024 + 512 + f0);
    *(float4*)(be + 4) = *(const float4*)(gbuf + b * 1024 + 512 + f0 + 4);
    float v[8];
    *(float4*)(v)     = *(float4*)(y + i8);
    *(float4*)(v + 4) = *(float4*)(y + i8 + 4);
    #pragma unroll
    for (int i = 0; i < 8; ++i) {
        float mu  = s[i] * (1.0f / 4096.0f);
        float var = q[i] * (1.0f / 4096.0f) - mu * mu;
        float A   = rsqrtf(var + EPS) * (1.0f + g[i]);
        float C   = be[i] - mu * A;
        v[i] = v[i] * A + C;
    }
    *(float4*)(y + i8)     = *(float4*)(v);
    *(float4*)(y + i8 + 4) = *(float4*)(v + 4);
}

extern "C" void kernel_launch(void* const* d_in, const int* in_sizes, int n_in,
                              void* d_out, int out_size, void* d_ws, size_t ws_size,
                              hipStream_t stream) {
    const float* x     = (const float*)d_in[0];
    const float* dl    = (const float*)d_in[1];
    const float* noise = (const float*)d_in[2];
    const float* w     = (const float*)d_in[3];
    const float* nw    = (const float*)d_in[4];
    const float* bias  = (const float*)d_in[5];
    const float* dw    = (const float*)d_in[6];
    const float* db    = (const float*)d_in[7];
    float* out = (float*)d_out;

    char* ws = (char*)d_ws;
    u16*   wts   = (u16*)ws;                       // 512 KB
    float* sum   = (float*)(ws + 524288);          // 16 KB
    float* sumsq = (float*)(ws + 540672);          // 16 KB (contiguous with sum)
    float* gbuf  = (float*)(ws + 557056);          // 32 KB

    k_prep<<<1153, 256, 0, stream>>>(w, wts, dl, dw, db, gbuf, sum);
    k_gemm<<<1024, 256, 0, stream>>>(x, wts, noise, nw, bias, out, sum, sumsq);
    k_norm<<<8192, 256, 0, stream>>>(out, sum, sumsq, gbuf);
}